// Round 2
// baseline (295.769 us; speedup 1.0000x reference)
//
#include <hip/hip_runtime.h>
#include <hip/hip_bf16.h>

#define NNEI 255

typedef __bf16 bf16_t;
typedef __bf16 bf16x8 __attribute__((ext_vector_type(8)));
typedef float f32x4 __attribute__((ext_vector_type(4)));

__device__ __forceinline__ float fast_tanh(float x) {
    float e = __expf(2.f * x);
    return 1.f - 2.f / (e + 1.f);   // e=inf -> 1, e=0 -> -1 : no NaN
}

__global__ __launch_bounds__(256, 2)
void raa_kernel(const float* __restrict__ q_x, const float* __restrict__ kv_x,
                const float* __restrict__ Wk, const float* __restrict__ Wq,
                const float* __restrict__ Wv, const float* __restrict__ bias,
                const float* __restrict__ score_w, float* __restrict__ out) {
    // LDS: WkT 32KB + ~5KB small buffers. Occupancy is VGPR-limited (2 blocks/CU).
    __shared__ __align__(16) unsigned char sWkT[128 * 256]; // bf16 [n][kk], permuted k, XOR-swizzled
    __shared__ float sQ[128];
    __shared__ float sQBp[2][128];
    __shared__ float sQB[128];
    __shared__ float sM[4], sL[4];
    __shared__ __align__(16) float sAcc[4][128];
    __shared__ float sXP[128];

    const int bt = blockIdx.x;
    const int tid = threadIdx.x;
    const int lane = tid & 63;
    const int w = tid >> 6;
    const int r0 = lane & 15;
    const int g4 = lane >> 4;

    if (tid < 128) sQ[tid] = q_x[bt * 128 + tid];

    // ---- stage Wk^T once, bf16, k-order permuted to match A-frag assignment:
    // position kk = ks*32 + g*8 + e  holds  Wk[orig k = g*32 + ks*8 + e][n]
    {
        int j = tid >> 1, i0 = (tid & 1) * 64;
        #pragma unroll
        for (int s8 = 0; s8 < 8; ++s8) {
            int kk0 = i0 + s8 * 8;
            int ks = kk0 >> 5, gs = (kk0 >> 3) & 3;
            bf16x8 pk;
            #pragma unroll
            for (int u = 0; u < 8; ++u)
                pk[u] = (bf16_t)Wk[(gs * 32 + ks * 8 + u) * 128 + j];
            unsigned off = (unsigned)(j * 256 + kk0 * 2) ^ ((unsigned)(j & 7) << 4);
            *(bf16x8*)(sWkT + off) = pk;
        }
    }
    __syncthreads();

    // ---- qb = q @ Wq + bias (split over 256 threads; score_b softmax-invariant) ----
    {
        int j = tid & 127, h = tid >> 7;
        float a = 0.f;
        for (int i = h * 64; i < h * 64 + 64; ++i)
            a = fmaf(sQ[i], Wq[i * 128 + j], a);
        sQBp[h][j] = a;
    }
    __syncthreads();
    if (tid < 128) sQB[tid] = sQBp[0][tid] + sQBp[1][tid] + bias[tid];
    __syncthreads();

    float qb_r[8], sw_r[8];
    #pragma unroll
    for (int jt = 0; jt < 8; ++jt) {
        qb_r[jt] = sQB[jt * 16 + r0];
        sw_r[jt] = score_w[jt * 16 + r0];
    }

    const float4* kv4 = (const float4*)(kv_x) + (size_t)bt * (NNEI * 32);

    float m_run = -3e38f, l_run = 0.f;
    float acc[32];
    #pragma unroll
    for (int u = 0; u < 32; ++u) acc[u] = 0.f;

    #pragma unroll
    for (int p = 0; p < 2; ++p) {
        const int rbase = w * 64 + p * 32;
        // ---- direct global load: lane (r0,g4) owns rows rbase+t*16+r0, bytes [g4*128, +128) ----
        float4 v[2][8];
        #pragma unroll
        for (int t = 0; t < 2; ++t) {
            int row = rbase + t * 16 + r0;
            int rowc = row < NNEI ? row : NNEI - 1;
            const float4* src = kv4 + rowc * 32 + g4 * 8;
            #pragma unroll
            for (int i = 0; i < 8; ++i) v[t][i] = src[i];
        }
        bf16x8 afr[2][4];
        #pragma unroll
        for (int t = 0; t < 2; ++t) {
            #pragma unroll
            for (int ks = 0; ks < 4; ++ks) {
                bf16x8 f;
                f[0] = (bf16_t)v[t][2 * ks].x;     f[1] = (bf16_t)v[t][2 * ks].y;
                f[2] = (bf16_t)v[t][2 * ks].z;     f[3] = (bf16_t)v[t][2 * ks].w;
                f[4] = (bf16_t)v[t][2 * ks + 1].x; f[5] = (bf16_t)v[t][2 * ks + 1].y;
                f[6] = (bf16_t)v[t][2 * ks + 1].z; f[7] = (bf16_t)v[t][2 * ks + 1].w;
                afr[t][ks] = f;
            }
        }
        // ---- keys = kv @ Wk via MFMA; one B read feeds both M-tiles ----
        f32x4 Ck[2][8];
        #pragma unroll
        for (int t = 0; t < 2; ++t)
            #pragma unroll
            for (int jt = 0; jt < 8; ++jt) Ck[t][jt] = (f32x4){0.f, 0.f, 0.f, 0.f};
        #pragma unroll
        for (int ks = 0; ks < 4; ++ks) {
            #pragma unroll
            for (int jt = 0; jt < 8; ++jt) {
                int n = jt * 16 + r0;
                bf16x8 bfr = *(const bf16x8*)(sWkT +
                    (((unsigned)(n * 256 + ks * 64 + g4 * 16)) ^ ((unsigned)(n & 7) << 4)));
                Ck[0][jt] = __builtin_amdgcn_mfma_f32_16x16x32_bf16(afr[0][ks], bfr, Ck[0][jt], 0, 0, 0);
                Ck[1][jt] = __builtin_amdgcn_mfma_f32_16x16x32_bf16(afr[1][ks], bfr, Ck[1][jt], 0, 0, 0);
            }
        }
        // ---- scores: sum_j tanh(key + qb) * sw ; C layout col=r0, row=g4*4+reg ----
        float part[2][4];
        #pragma unroll
        for (int t = 0; t < 2; ++t)
            #pragma unroll
            for (int reg = 0; reg < 4; ++reg) part[t][reg] = 0.f;
        #pragma unroll
        for (int jt = 0; jt < 8; ++jt) {
            #pragma unroll
            for (int t = 0; t < 2; ++t) {
                #pragma unroll
                for (int reg = 0; reg < 4; ++reg) {
                    float x = Ck[t][jt][reg] + qb_r[jt];
                    part[t][reg] = fmaf(fast_tanh(x), sw_r[jt], part[t][reg]);
                }
            }
        }
        #pragma unroll
        for (int off = 1; off < 16; off <<= 1) {
            #pragma unroll
            for (int t = 0; t < 2; ++t)
                #pragma unroll
                for (int reg = 0; reg < 4; ++reg)
                    part[t][reg] += __shfl_xor(part[t][reg], off);
        }
        #pragma unroll
        for (int t = 0; t < 2; ++t) {
            #pragma unroll
            for (int reg = 0; reg < 4; ++reg) {
                int n = rbase + t * 16 + g4 * 4 + reg;
                if (n >= NNEI) part[t][reg] = -1e30f;
            }
        }
        // ---- online softmax over this pair's 32 rows ----
        float cm = part[0][0];
        #pragma unroll
        for (int t = 0; t < 2; ++t)
            #pragma unroll
            for (int reg = 0; reg < 4; ++reg) cm = fmaxf(cm, part[t][reg]);
        cm = fmaxf(cm, __shfl_xor(cm, 16));
        cm = fmaxf(cm, __shfl_xor(cm, 32));
        float mn = fmaxf(m_run, cm);
        float scale = __expf(m_run - mn);
        float pv[2][4];
        float ps = 0.f;
        #pragma unroll
        for (int t = 0; t < 2; ++t)
            #pragma unroll
            for (int reg = 0; reg < 4; ++reg) {
                pv[t][reg] = __expf(part[t][reg] - mn);
                ps += pv[t][reg];
            }
        ps += __shfl_xor(ps, 16);
        ps += __shfl_xor(ps, 32);
        l_run = l_run * scale + ps;
        m_run = mn;
        #pragma unroll
        for (int u = 0; u < 32; ++u) acc[u] *= scale;
        // ---- weighted accumulate from the bf16 frags still in registers ----
        #pragma unroll
        for (int t = 0; t < 2; ++t) {
            int src = (r0 >> 2) * 16;      // group holding p for row r0 of this tile
            float a0 = __shfl(pv[t][0], src), a1 = __shfl(pv[t][1], src);
            float a2 = __shfl(pv[t][2], src), a3 = __shfl(pv[t][3], src);
            float pr = (r0 & 2) ? ((r0 & 1) ? a3 : a2) : ((r0 & 1) ? a1 : a0);
            #pragma unroll
            for (int ks = 0; ks < 4; ++ks)
                #pragma unroll
                for (int u = 0; u < 8; ++u)
                    acc[ks * 8 + u] = fmaf(pr, (float)afr[t][ks][u], acc[ks * 8 + u]);
        }
    }

    // ---- reduce acc over the 16 row-lanes; lane covers k = g4*32 + [0,32) ----
    #pragma unroll
    for (int off = 1; off < 16; off <<= 1)
        #pragma unroll
        for (int u = 0; u < 32; ++u)
            acc[u] += __shfl_xor(acc[u], off);
    if (r0 == 0) {
        #pragma unroll
        for (int i = 0; i < 8; ++i) {
            float4 o = make_float4(acc[4 * i], acc[4 * i + 1], acc[4 * i + 2], acc[4 * i + 3]);
            *(float4*)&sAcc[w][g4 * 32 + 4 * i] = o;
        }
    }
    if (lane == 0) { sM[w] = m_run; sL[w] = l_run; }
    __syncthreads();

    // ---- cross-wave flash combine ----
    if (tid < 128) {
        float M4 = fmaxf(fmaxf(sM[0], sM[1]), fmaxf(sM[2], sM[3]));
        float f0 = __expf(sM[0] - M4), f1 = __expf(sM[1] - M4);
        float f2 = __expf(sM[2] - M4), f3 = __expf(sM[3] - M4);
        float L = f0 * sL[0] + f1 * sL[1] + f2 * sL[2] + f3 * sL[3];
        float xp = f0 * sAcc[0][tid] + f1 * sAcc[1][tid]
                 + f2 * sAcc[2][tid] + f3 * sAcc[3][tid];
        sXP[tid] = xp / L;
    }
    __syncthreads();

    // ---- x = (sum_n w_n kv_n) @ Wv, split over 256 threads ----
    {
        int j = tid & 127, h = tid >> 7;
        float o = 0.f;
        for (int i = h * 64; i < h * 64 + 64; ++i)
            o = fmaf(sXP[i], Wv[i * 128 + j], o);
        sQBp[h][j] = o;
    }
    __syncthreads();
    if (tid < 128) out[(size_t)bt * 128 + tid] = sQBp[0][tid] + sQBp[1][tid];
}

extern "C" void kernel_launch(void* const* d_in, const int* in_sizes, int n_in,
                              void* d_out, int out_size, void* d_ws, size_t ws_size,
                              hipStream_t stream) {
    const float* q_x     = (const float*)d_in[0];
    const float* kv_x    = (const float*)d_in[1];
    const float* Wk      = (const float*)d_in[2];
    const float* Wq      = (const float*)d_in[3];
    const float* Wv      = (const float*)d_in[4];
    const float* bias    = (const float*)d_in[5];
    const float* score_w = (const float*)d_in[6];
    // score_b (d_in[7]) is softmax-invariant: dropped.
    float* out = (float*)d_out;

    raa_kernel<<<dim3(2048), dim3(256), 0, stream>>>(
        q_x, kv_x, Wk, Wq, Wv, bias, score_w, out);
}